// Round 4
// baseline (198.616 us; speedup 1.0000x reference)
//
#include <hip/hip_runtime.h>
#include <hip/hip_bf16.h>

typedef unsigned short u16;
typedef __attribute__((ext_vector_type(8))) __bf16 bf16x8;
typedef __attribute__((ext_vector_type(4))) float f32x4;

#define S_LEN 2048
#define DMODEL 1024
#define NHEAD 16
#define HSZ 64

__device__ __forceinline__ u16 f2bf(float f) {
  union { __hip_bfloat16 b; u16 u; } c;
  c.b = __float2bfloat16(f);
  return c.u;
}

__device__ __forceinline__ float bf2f(u16 u) {
  union { unsigned int i; float f; } c;
  c.i = ((unsigned int)u) << 16;
  return c.f;
}

__device__ __forceinline__ void gload_lds16(const void* g, void* l) {
  __builtin_amdgcn_global_load_lds(
      (const __attribute__((address_space(1))) void*)g,
      (__attribute__((address_space(3))) void*)l, 16, 0, 0);
}

__device__ __forceinline__ f32x4 mfma16(bf16x8 a, bf16x8 b, f32x4 c) {
  return __builtin_amdgcn_mfma_f32_16x16x32_bf16(a, b, c, 0, 0, 0);
}

// ---------------- fp32 -> bf16 convert (vectorized) ----------------
__global__ __launch_bounds__(256) void convert_f2b_kernel(const float* __restrict__ in,
                                                          u16* __restrict__ out) {
  int i = (blockIdx.x * 256 + threadIdx.x) * 4;
  float4 v = *(const float4*)(in + i);
  ushort4 o;
  o.x = f2bf(v.x); o.y = f2bf(v.y); o.z = f2bf(v.z); o.w = f2bf(v.w);
  *(ushort4*)(out + i) = o;
}

// ------------- W [K][N] fp32 -> W^T [N][K] bf16 (LDS tiled) -------------
__global__ __launch_bounds__(256) void transpose_w_kernel(
    const float* __restrict__ W0, const float* __restrict__ W1,
    const float* __restrict__ W2, const float* __restrict__ W3,
    u16* __restrict__ T0, u16* __restrict__ T1,
    u16* __restrict__ T2, u16* __restrict__ T3) {
  int z = blockIdx.z;
  const float* W = (z == 0) ? W0 : ((z == 1) ? W1 : ((z == 2) ? W2 : W3));
  u16* T = (z == 0) ? T0 : ((z == 1) ? T1 : ((z == 2) ? T2 : T3));
  __shared__ float tile[64][65];
  int t = threadIdx.x;
  int k0 = blockIdx.y * 64, n0 = blockIdx.x * 64;
#pragma unroll
  for (int j = 0; j < 4; ++j) {
    int idx = j * 256 + t;
    int row = idx >> 4, c4 = idx & 15;
    float4 v = *(const float4*)(W + (size_t)(k0 + row) * DMODEL + n0 + c4 * 4);
    tile[row][c4 * 4 + 0] = v.x; tile[row][c4 * 4 + 1] = v.y;
    tile[row][c4 * 4 + 2] = v.z; tile[row][c4 * 4 + 3] = v.w;
  }
  __syncthreads();
#pragma unroll
  for (int j = 0; j < 4; ++j) {
    int idx = j * 256 + t;
    int orow = idx >> 4, c4 = idx & 15;
    ushort4 o;
    o.x = f2bf(tile[c4 * 4 + 0][orow]);
    o.y = f2bf(tile[c4 * 4 + 1][orow]);
    o.z = f2bf(tile[c4 * 4 + 2][orow]);
    o.w = f2bf(tile[c4 * 4 + 3][orow]);
    *(ushort4*)(T + (size_t)(n0 + orow) * DMODEL + k0 + c4 * 4) = o;
  }
}

// ------------- Vh [bh][S][64] -> Vt [bh][64][S] bf16 -------------
__global__ __launch_bounds__(256) void transpose_v_kernel(const u16* __restrict__ Vh,
                                                          u16* __restrict__ Vt) {
  int bh = blockIdx.y;
  int s0 = blockIdx.x * 64;
  __shared__ __align__(16) u16 tile[64][72];
  int t = threadIdx.x;
#pragma unroll
  for (int j = 0; j < 4; ++j) {
    int idx = j * 256 + t;
    int row = idx >> 4, c4 = idx & 15;
    *(ushort4*)&tile[row][c4 * 4] =
        *(const ushort4*)(Vh + ((size_t)bh * S_LEN + s0 + row) * HSZ + c4 * 4);
  }
  __syncthreads();
#pragma unroll
  for (int j = 0; j < 4; ++j) {
    int idx = j * 256 + t;
    int orow = idx >> 4, c4 = idx & 15;
    ushort4 o;
    o.x = tile[c4 * 4 + 0][orow];
    o.y = tile[c4 * 4 + 1][orow];
    o.z = tile[c4 * 4 + 2][orow];
    o.w = tile[c4 * 4 + 3][orow];
    *(ushort4*)(Vt + ((size_t)bh * HSZ + orow) * S_LEN + s0 + c4 * 4) = o;
  }
}

// ------------- GEMM core, templated on m-frags/wave (WM*32 = tile rows) -------------
template <int WM>
__device__ __forceinline__ void gemm_core(const u16* __restrict__ A,
                                          const u16* __restrict__ Bt,
                                          u16* ldsbuf, f32x4 (&acc)[WM][4],
                                          int m0, int n0) {
  const int t = threadIdx.x;
  const int wave = t >> 6, lane = t & 63;
  const int l15 = lane & 15, l4 = lane >> 4;
  const int wr = wave >> 1, wc = wave & 1;
  u16* Asm = ldsbuf;                 // [WM*32][32]
  u16* Bsm = ldsbuf + WM * 1024;     // [128][32]
  for (int kt = 0; kt < DMODEL / 32; ++kt) {
    int kb = kt * 32;
#pragma unroll
    for (int j = 0; j < WM / 2; ++j) {
      int ci = j * 256 + t;
      int row = ci >> 2, kc = ci & 3;
      gload_lds16(A + (size_t)(m0 + row) * DMODEL + kb + kc * 8,
                  Asm + (j * 256 + wave * 64) * 8);
    }
#pragma unroll
    for (int j = 0; j < 2; ++j) {
      int ci = j * 256 + t;
      int row = ci >> 2, kc = ci & 3;
      gload_lds16(Bt + (size_t)(n0 + row) * DMODEL + kb + kc * 8,
                  Bsm + (j * 256 + wave * 64) * 8);
    }
    __syncthreads();
    bf16x8 af[WM], bfr[4];
#pragma unroll
    for (int m = 0; m < WM; ++m)
      af[m] = *(const bf16x8*)(Asm + ((wr * (WM * 16) + m * 16 + l15) * 32 + l4 * 8));
#pragma unroll
    for (int n = 0; n < 4; ++n)
      bfr[n] = *(const bf16x8*)(Bsm + ((wc * 64 + n * 16 + l15) * 32 + l4 * 8));
#pragma unroll
    for (int m = 0; m < WM; ++m)
#pragma unroll
      for (int n = 0; n < 4; ++n)
        acc[m][n] = mfma16(af[m], bfr[n], acc[m][n]);
    __syncthreads();
  }
}

// ------------- QKV projection; Q output pre-scaled by 1/sqrt(HS) -------------
__global__ __launch_bounds__(256) void gemm_qkv_kernel(
    const u16* __restrict__ A, const u16* __restrict__ B0, const u16* __restrict__ B1,
    const u16* __restrict__ B2, const float* __restrict__ bias0,
    const float* __restrict__ bias1, const float* __restrict__ bias2,
    u16* __restrict__ d0, u16* __restrict__ d1, u16* __restrict__ d2) {
  __shared__ __align__(16) u16 lds[8192];
  int z = blockIdx.z;
  const u16* Bt = (z == 0) ? B0 : ((z == 1) ? B1 : B2);
  const float* bias = (z == 0) ? bias0 : ((z == 1) ? bias1 : bias2);
  u16* dst = (z == 0) ? d0 : ((z == 1) ? d1 : d2);
  const float sc = (z == 0) ? 0.125f : 1.0f;  // 1/sqrt(64), exact pow2
  int m0 = blockIdx.y * 128, n0 = blockIdx.x * 128;
  f32x4 acc[4][4] = {};
  gemm_core<4>(A, Bt, lds, acc, m0, n0);
  const int t = threadIdx.x;
  const int wave = t >> 6, lane = t & 63, l15 = lane & 15, l4 = lane >> 4;
  const int wr = wave >> 1, wc = wave & 1;
#pragma unroll
  for (int n = 0; n < 4; ++n) {
    int colg = n0 + wc * 64 + n * 16 + l15;
    float bn = bias[colg];
    int h = colg >> 6, hs = colg & 63;
#pragma unroll
    for (int m = 0; m < 4; ++m) {
#pragma unroll
      for (int i = 0; i < 4; ++i) {
        int rowg = m0 + wr * 64 + m * 16 + 4 * l4 + i;
        int b = rowg >> 11, s = rowg & 2047;
        dst[(size_t)(b * NHEAD + h) * S_LEN * HSZ + (size_t)s * HSZ + hs] =
            f2bf((acc[m][n][i] + bn) * sc);
      }
    }
  }
}

// ------------- output projection: 64x128 tile, fp32 out -------------
__global__ __launch_bounds__(256) void gemm_out_kernel(const u16* __restrict__ A,
                                                       const u16* __restrict__ Bt,
                                                       const float* __restrict__ bias,
                                                       float* __restrict__ out) {
  __shared__ __align__(16) u16 lds[6144];
  int m0 = blockIdx.y * 64, n0 = blockIdx.x * 128;
  f32x4 acc[2][4] = {};
  gemm_core<2>(A, Bt, lds, acc, m0, n0);
  const int t = threadIdx.x;
  const int wave = t >> 6, lane = t & 63, l15 = lane & 15, l4 = lane >> 4;
  const int wr = wave >> 1, wc = wave & 1;
#pragma unroll
  for (int n = 0; n < 4; ++n) {
    int colg = n0 + wc * 64 + n * 16 + l15;
    float bn = bias[colg];
#pragma unroll
    for (int m = 0; m < 2; ++m) {
#pragma unroll
      for (int i = 0; i < 4; ++i) {
        int rowg = m0 + wr * 32 + m * 16 + 4 * l4 + i;
        out[(size_t)rowg * DMODEL + colg] = acc[m][n][i] + bn;
      }
    }
  }
}

// ------------- flash attention (causal), split-KV across 4 waves -------------
// Block = one 32-row q-tile of one bh; wave w handles kv tiles {w, w+4, ...}.
// Private (m,l,O) per wave; one barrier; LDS merge with exp rescale.
// Swapped QK^T (S^T in regs): row(4*l4+i)=kv-sub, col(l15)=q-sub.
// XCD mapping: id&7 = xcd -> heads 4x..4x+3 keep K/V (2MB) in local L2.
__global__ __launch_bounds__(256, 4) void attn_kernel(const u16* __restrict__ Qh,
                                                      const u16* __restrict__ Kh,
                                                      const u16* __restrict__ Vt,
                                                      u16* __restrict__ Ob) {
  __shared__ __align__(16) u16 Pl[4][32][72];
  __shared__ __align__(16) u16 Opart[4][32][72];
  __shared__ float Ml[4][32];
  __shared__ float Ll[4][32];
  const int tixd = threadIdx.x;
  const int wave = tixd >> 6, lane = tixd & 63;
  const int l15 = lane & 15, l4 = lane >> 4;
  const int id = blockIdx.x;
  const int bh = (id & 7) * 4 + ((id >> 3) & 3);  // XCD-local heads
  const int tt = id >> 5;
  const int q0 = tt * 32;
  const int ntile = (tt >> 1) + 1;
  const u16* Qb = Qh + (size_t)bh * S_LEN * HSZ;
  const u16* Kb = Kh + (size_t)bh * S_LEN * HSZ;
  const u16* Vb = Vt + (size_t)bh * HSZ * S_LEN;
  const int shbase = l4 * 20;  // lane with l15' = 4*l4+i, same l4
  u16 (*P)[72] = Pl[wave];

  bf16x8 qf[2][2];
#pragma unroll
  for (int m = 0; m < 2; ++m)
#pragma unroll
    for (int kc = 0; kc < 2; ++kc)
      qf[m][kc] = *(const bf16x8*)(Qb + (size_t)(q0 + m * 16 + l15) * HSZ + kc * 32 + l4 * 8);

  f32x4 oacc[2][4] = {};
  float mrun[2] = {-1e30f, -1e30f};
  float lrun[2] = {0.f, 0.f};

  auto loadK = [&](int kv0, bf16x8 (&kf)[4][2]) {
#pragma unroll
    for (int n = 0; n < 4; ++n)
#pragma unroll
      for (int kc = 0; kc < 2; ++kc)
        kf[n][kc] = *(const bf16x8*)(Kb + (size_t)(kv0 + n * 16 + l15) * HSZ + kc * 32 + l4 * 8);
  };

  auto process = [&](int kv0, bf16x8 (&kf)[4][2]) {
    f32x4 sacc[2][4] = {};
#pragma unroll
    for (int m = 0; m < 2; ++m)
#pragma unroll
      for (int n = 0; n < 4; ++n) {
        sacc[m][n] = mfma16(kf[n][0], qf[m][0], sacc[m][n]);
        sacc[m][n] = mfma16(kf[n][1], qf[m][1], sacc[m][n]);
      }
    // V fragments issued here: latency hides under mask+softmax chain
    bf16x8 vf[2][4];
#pragma unroll
    for (int kb = 0; kb < 2; ++kb)
#pragma unroll
      for (int n = 0; n < 4; ++n)
        vf[kb][n] = *(const bf16x8*)(Vb + (size_t)(n * 16 + l15) * S_LEN + kv0 + kb * 32 + l4 * 8);
    if (kv0 + 63 > q0) {
#pragma unroll
      for (int m = 0; m < 2; ++m)
#pragma unroll
        for (int n = 0; n < 4; ++n)
#pragma unroll
          for (int i = 0; i < 4; ++i)
            if (kv0 + n * 16 + 4 * l4 + i > q0 + m * 16 + l15) sacc[m][n][i] = -1e30f;
    }
#pragma unroll
    for (int m = 0; m < 2; ++m) {
      float tm = sacc[m][0][0];
#pragma unroll
      for (int n = 0; n < 4; ++n)
#pragma unroll
        for (int i = 0; i < 4; ++i) tm = fmaxf(tm, sacc[m][n][i]);
      tm = fmaxf(tm, __shfl_xor(tm, 16));
      tm = fmaxf(tm, __shfl_xor(tm, 32));
      float mnew = fmaxf(mrun[m], tm);
      float corr = __expf(mrun[m] - mnew);
      mrun[m] = mnew;
      float rs = 0.f;
#pragma unroll
      for (int n = 0; n < 4; ++n)
#pragma unroll
        for (int i = 0; i < 4; ++i) {
          float p = __expf(sacc[m][n][i] - mnew);
          sacc[m][n][i] = p;
          rs += p;
        }
      rs += __shfl_xor(rs, 16);
      rs += __shfl_xor(rs, 32);
      lrun[m] = lrun[m] * corr + rs;
      float c0 = __shfl(corr, shbase + 0);
      float c1 = __shfl(corr, shbase + 1);
      float c2 = __shfl(corr, shbase + 2);
      float c3 = __shfl(corr, shbase + 3);
#pragma unroll
      for (int n = 0; n < 4; ++n) {
        oacc[m][n][0] *= c0; oacc[m][n][1] *= c1;
        oacc[m][n][2] *= c2; oacc[m][n][3] *= c3;
      }
#pragma unroll
      for (int n = 0; n < 4; ++n) {
        ushort4 pk;
        pk.x = f2bf(sacc[m][n][0]); pk.y = f2bf(sacc[m][n][1]);
        pk.z = f2bf(sacc[m][n][2]); pk.w = f2bf(sacc[m][n][3]);
        *(ushort4*)&P[m * 16 + l15][n * 16 + 4 * l4] = pk;
      }
    }
#pragma unroll
    for (int kb = 0; kb < 2; ++kb) {
      bf16x8 pf0 = *(const bf16x8*)&P[l15][kb * 32 + l4 * 8];
      bf16x8 pf1 = *(const bf16x8*)&P[16 + l15][kb * 32 + l4 * 8];
#pragma unroll
      for (int n = 0; n < 4; ++n) {
        oacc[0][n] = mfma16(pf0, vf[kb][n], oacc[0][n]);
        oacc[1][n] = mfma16(pf1, vf[kb][n], oacc[1][n]);
      }
    }
  };

  const int nt = (ntile > wave) ? ((ntile - wave + 3) >> 2) : 0;
  bf16x8 kA[4][2];
  for (int j = 0; j < nt; ++j) {
    const int kv0 = (wave + 4 * j) * 64;
    loadK(kv0, kA);
    process(kv0, kA);
  }

  // publish partials (rows: q = m*16 + l15 for m/l; q = m*16+4*l4+i for O)
  if (l4 == 0) {
#pragma unroll
    for (int m = 0; m < 2; ++m) {
      Ml[wave][m * 16 + l15] = mrun[m];
      Ll[wave][m * 16 + l15] = lrun[m];
    }
  }
#pragma unroll
  for (int m = 0; m < 2; ++m)
#pragma unroll
    for (int n = 0; n < 4; ++n)
#pragma unroll
      for (int i = 0; i < 4; ++i)
        Opart[wave][m * 16 + 4 * l4 + i][n * 16 + l15] = f2bf(oacc[m][n][i]);
  __syncthreads();

  // merge: thread t -> row r = t>>3, col chunk c0 = (t&7)*8
  {
    const int r = tixd >> 3;
    const int c0 = (tixd & 7) * 8;
    float m0v = Ml[0][r], m1v = Ml[1][r], m2v = Ml[2][r], m3v = Ml[3][r];
    float M = fmaxf(fmaxf(m0v, m1v), fmaxf(m2v, m3v));
    float e0 = __expf(m0v - M), e1 = __expf(m1v - M);
    float e2 = __expf(m2v - M), e3 = __expf(m3v - M);
    float L = Ll[0][r] * e0 + Ll[1][r] * e1 + Ll[2][r] * e2 + Ll[3][r] * e3;
    float invL = 1.0f / L;
    bf16x8 o0 = *(const bf16x8*)&Opart[0][r][c0];
    bf16x8 o1 = *(const bf16x8*)&Opart[1][r][c0];
    bf16x8 o2 = *(const bf16x8*)&Opart[2][r][c0];
    bf16x8 o3 = *(const bf16x8*)&Opart[3][r][c0];
    const int b = bh >> 4, h = bh & 15;
    const int srow = q0 + r;
    u16* dst = Ob + ((size_t)b * S_LEN + srow) * DMODEL + h * HSZ + c0;
    ushort4 w0, w1;
    u16* wp[2] = {(u16*)&w0, (u16*)&w1};
#pragma unroll
    for (int j = 0; j < 8; ++j) {
      float acc = bf2f(((u16*)&o0)[j] /*bf16 bits*/) * e0;
      acc += bf2f(((u16*)&o1)[j]) * e1;
      acc += bf2f(((u16*)&o2)[j]) * e2;
      acc += bf2f(((u16*)&o3)[j]) * e3;
      wp[j >> 2][j & 3] = f2bf(acc * invL);
    }
    *(ushort4*)(dst + 0) = w0;
    *(ushort4*)(dst + 4) = w1;
  }
}

extern "C" void kernel_launch(void* const* d_in, const int* in_sizes, int n_in,
                              void* d_out, int out_size, void* d_ws, size_t ws_size,
                              hipStream_t stream) {
  const float* q  = (const float*)d_in[0];
  const float* Wq = (const float*)d_in[1];
  const float* bq = (const float*)d_in[2];
  const float* Wk = (const float*)d_in[3];
  const float* bk = (const float*)d_in[4];
  const float* Wv = (const float*)d_in[5];
  const float* bv = (const float*)d_in[6];
  const float* Wo = (const float*)d_in[7];
  const float* bo = (const float*)d_in[8];

  char* ws = (char*)d_ws;
  const size_t MB = 1024 * 1024;
  u16* Xb  = (u16*)(ws + 0);        // 8 MB  [4096][1024] bf16
  u16* WqT = (u16*)(ws + 8 * MB);   // 2 MB  [N][K] bf16
  u16* WkT = (u16*)(ws + 10 * MB);
  u16* WvT = (u16*)(ws + 12 * MB);
  u16* WoT = (u16*)(ws + 14 * MB);
  u16* Qh  = (u16*)(ws + 16 * MB);  // 8 MB  [bh][S][64]
  u16* Kh  = (u16*)(ws + 24 * MB);
  u16* Vh  = (u16*)(ws + 32 * MB);
  u16* Vt  = (u16*)(ws + 40 * MB);  // 8 MB  [bh][64][S]
  u16* Ob  = (u16*)(ws + 48 * MB);  // 8 MB  [B,S,D]

  convert_f2b_kernel<<<4096, 256, 0, stream>>>(q, Xb);
  transpose_w_kernel<<<dim3(16, 16, 4), 256, 0, stream>>>(Wq, Wk, Wv, Wo,
                                                          WqT, WkT, WvT, WoT);
  gemm_qkv_kernel<<<dim3(8, 32, 3), 256, 0, stream>>>(Xb, WqT, WkT, WvT,
                                                      bq, bk, bv, Qh, Kh, Vh);
  transpose_v_kernel<<<dim3(32, 32), 256, 0, stream>>>(Vh, Vt);
  attn_kernel<<<2048, 256, 0, stream>>>(Qh, Kh, Vt, Ob);
  gemm_out_kernel<<<dim3(8, 64), 256, 0, stream>>>(Ob, WoT, bo, (float*)d_out);
}

// Round 5
// 136.712 us; speedup vs baseline: 1.4528x; 1.4528x over previous
//
#include <hip/hip_runtime.h>
#include <hip/hip_bf16.h>

typedef unsigned short u16;
typedef __attribute__((ext_vector_type(8))) __bf16 bf16x8;
typedef __attribute__((ext_vector_type(4))) float f32x4;

#define S_LEN 2048
#define DMODEL 1024
#define NHEAD 16
#define HSZ 64

__device__ __forceinline__ u16 f2bf(float f) {
  union { __hip_bfloat16 b; u16 u; } c;
  c.b = __float2bfloat16(f);
  return c.u;
}

__device__ __forceinline__ float bf2f(u16 u) {
  union { unsigned int i; float f; } c;
  c.i = ((unsigned int)u) << 16;
  return c.f;
}

__device__ __forceinline__ void gload_lds16(const void* g, void* l) {
  __builtin_amdgcn_global_load_lds(
      (const __attribute__((address_space(1))) void*)g,
      (__attribute__((address_space(3))) void*)l, 16, 0, 0);
}

__device__ __forceinline__ f32x4 mfma16(bf16x8 a, bf16x8 b, f32x4 c) {
  return __builtin_amdgcn_mfma_f32_16x16x32_bf16(a, b, c, 0, 0, 0);
}

// ---------------- fp32 -> bf16 convert (vectorized) ----------------
__global__ __launch_bounds__(256) void convert_f2b_kernel(const float* __restrict__ in,
                                                          u16* __restrict__ out) {
  int i = (blockIdx.x * 256 + threadIdx.x) * 4;
  float4 v = *(const float4*)(in + i);
  ushort4 o;
  o.x = f2bf(v.x); o.y = f2bf(v.y); o.z = f2bf(v.z); o.w = f2bf(v.w);
  *(ushort4*)(out + i) = o;
}

// ------------- W [K][N] fp32 -> W^T [N][K] bf16 (LDS tiled) -------------
__global__ __launch_bounds__(256) void transpose_w_kernel(
    const float* __restrict__ W0, const float* __restrict__ W1,
    const float* __restrict__ W2, const float* __restrict__ W3,
    u16* __restrict__ T0, u16* __restrict__ T1,
    u16* __restrict__ T2, u16* __restrict__ T3) {
  int z = blockIdx.z;
  const float* W = (z == 0) ? W0 : ((z == 1) ? W1 : ((z == 2) ? W2 : W3));
  u16* T = (z == 0) ? T0 : ((z == 1) ? T1 : ((z == 2) ? T2 : T3));
  __shared__ float tile[64][65];
  int t = threadIdx.x;
  int k0 = blockIdx.y * 64, n0 = blockIdx.x * 64;
#pragma unroll
  for (int j = 0; j < 4; ++j) {
    int idx = j * 256 + t;
    int row = idx >> 4, c4 = idx & 15;
    float4 v = *(const float4*)(W + (size_t)(k0 + row) * DMODEL + n0 + c4 * 4);
    tile[row][c4 * 4 + 0] = v.x; tile[row][c4 * 4 + 1] = v.y;
    tile[row][c4 * 4 + 2] = v.z; tile[row][c4 * 4 + 3] = v.w;
  }
  __syncthreads();
#pragma unroll
  for (int j = 0; j < 4; ++j) {
    int idx = j * 256 + t;
    int orow = idx >> 4, c4 = idx & 15;
    ushort4 o;
    o.x = f2bf(tile[c4 * 4 + 0][orow]);
    o.y = f2bf(tile[c4 * 4 + 1][orow]);
    o.z = f2bf(tile[c4 * 4 + 2][orow]);
    o.w = f2bf(tile[c4 * 4 + 3][orow]);
    *(ushort4*)(T + (size_t)(n0 + orow) * DMODEL + k0 + c4 * 4) = o;
  }
}

// ------------- Vh [bh][S][64] -> Vt [bh][64][S] bf16 -------------
__global__ __launch_bounds__(256) void transpose_v_kernel(const u16* __restrict__ Vh,
                                                          u16* __restrict__ Vt) {
  int bh = blockIdx.y;
  int s0 = blockIdx.x * 64;
  __shared__ __align__(16) u16 tile[64][72];
  int t = threadIdx.x;
#pragma unroll
  for (int j = 0; j < 4; ++j) {
    int idx = j * 256 + t;
    int row = idx >> 4, c4 = idx & 15;
    *(ushort4*)&tile[row][c4 * 4] =
        *(const ushort4*)(Vh + ((size_t)bh * S_LEN + s0 + row) * HSZ + c4 * 4);
  }
  __syncthreads();
#pragma unroll
  for (int j = 0; j < 4; ++j) {
    int idx = j * 256 + t;
    int orow = idx >> 4, c4 = idx & 15;
    ushort4 o;
    o.x = tile[c4 * 4 + 0][orow];
    o.y = tile[c4 * 4 + 1][orow];
    o.z = tile[c4 * 4 + 2][orow];
    o.w = tile[c4 * 4 + 3][orow];
    *(ushort4*)(Vt + ((size_t)bh * HSZ + orow) * S_LEN + s0 + c4 * 4) = o;
  }
}

// ------------- GEMM core, templated on m-frags/wave (WM*32 = tile rows) -------------
template <int WM>
__device__ __forceinline__ void gemm_core(const u16* __restrict__ A,
                                          const u16* __restrict__ Bt,
                                          u16* ldsbuf, f32x4 (&acc)[WM][4],
                                          int m0, int n0) {
  const int t = threadIdx.x;
  const int wave = t >> 6, lane = t & 63;
  const int l15 = lane & 15, l4 = lane >> 4;
  const int wr = wave >> 1, wc = wave & 1;
  u16* Asm = ldsbuf;                 // [WM*32][32]
  u16* Bsm = ldsbuf + WM * 1024;     // [128][32]
  for (int kt = 0; kt < DMODEL / 32; ++kt) {
    int kb = kt * 32;
#pragma unroll
    for (int j = 0; j < WM / 2; ++j) {
      int ci = j * 256 + t;
      int row = ci >> 2, kc = ci & 3;
      gload_lds16(A + (size_t)(m0 + row) * DMODEL + kb + kc * 8,
                  Asm + (j * 256 + wave * 64) * 8);
    }
#pragma unroll
    for (int j = 0; j < 2; ++j) {
      int ci = j * 256 + t;
      int row = ci >> 2, kc = ci & 3;
      gload_lds16(Bt + (size_t)(n0 + row) * DMODEL + kb + kc * 8,
                  Bsm + (j * 256 + wave * 64) * 8);
    }
    __syncthreads();
    bf16x8 af[WM], bfr[4];
#pragma unroll
    for (int m = 0; m < WM; ++m)
      af[m] = *(const bf16x8*)(Asm + ((wr * (WM * 16) + m * 16 + l15) * 32 + l4 * 8));
#pragma unroll
    for (int n = 0; n < 4; ++n)
      bfr[n] = *(const bf16x8*)(Bsm + ((wc * 64 + n * 16 + l15) * 32 + l4 * 8));
#pragma unroll
    for (int m = 0; m < WM; ++m)
#pragma unroll
      for (int n = 0; n < 4; ++n)
        acc[m][n] = mfma16(af[m], bfr[n], acc[m][n]);
    __syncthreads();
  }
}

// ------------- QKV projection; Q output pre-scaled by 1/sqrt(HS) -------------
__global__ __launch_bounds__(256) void gemm_qkv_kernel(
    const u16* __restrict__ A, const u16* __restrict__ B0, const u16* __restrict__ B1,
    const u16* __restrict__ B2, const float* __restrict__ bias0,
    const float* __restrict__ bias1, const float* __restrict__ bias2,
    u16* __restrict__ d0, u16* __restrict__ d1, u16* __restrict__ d2) {
  __shared__ __align__(16) u16 lds[8192];
  int z = blockIdx.z;
  const u16* Bt = (z == 0) ? B0 : ((z == 1) ? B1 : B2);
  const float* bias = (z == 0) ? bias0 : ((z == 1) ? bias1 : bias2);
  u16* dst = (z == 0) ? d0 : ((z == 1) ? d1 : d2);
  const float sc = (z == 0) ? 0.125f : 1.0f;  // 1/sqrt(64), exact pow2
  int m0 = blockIdx.y * 128, n0 = blockIdx.x * 128;
  f32x4 acc[4][4] = {};
  gemm_core<4>(A, Bt, lds, acc, m0, n0);
  const int t = threadIdx.x;
  const int wave = t >> 6, lane = t & 63, l15 = lane & 15, l4 = lane >> 4;
  const int wr = wave >> 1, wc = wave & 1;
#pragma unroll
  for (int n = 0; n < 4; ++n) {
    int colg = n0 + wc * 64 + n * 16 + l15;
    float bn = bias[colg];
    int h = colg >> 6, hs = colg & 63;
#pragma unroll
    for (int m = 0; m < 4; ++m) {
#pragma unroll
      for (int i = 0; i < 4; ++i) {
        int rowg = m0 + wr * 64 + m * 16 + 4 * l4 + i;
        int b = rowg >> 11, s = rowg & 2047;
        dst[(size_t)(b * NHEAD + h) * S_LEN * HSZ + (size_t)s * HSZ + hs] =
            f2bf((acc[m][n][i] + bn) * sc);
      }
    }
  }
}

// ------------- output projection: 64x128 tile, fp32 out -------------
__global__ __launch_bounds__(256) void gemm_out_kernel(const u16* __restrict__ A,
                                                       const u16* __restrict__ Bt,
                                                       const float* __restrict__ bias,
                                                       float* __restrict__ out) {
  __shared__ __align__(16) u16 lds[6144];
  int m0 = blockIdx.y * 64, n0 = blockIdx.x * 128;
  f32x4 acc[2][4] = {};
  gemm_core<2>(A, Bt, lds, acc, m0, n0);
  const int t = threadIdx.x;
  const int wave = t >> 6, lane = t & 63, l15 = lane & 15, l4 = lane >> 4;
  const int wr = wave >> 1, wc = wave & 1;
#pragma unroll
  for (int n = 0; n < 4; ++n) {
    int colg = n0 + wc * 64 + n * 16 + l15;
    float bn = bias[colg];
#pragma unroll
    for (int m = 0; m < 2; ++m) {
#pragma unroll
      for (int i = 0; i < 4; ++i) {
        int rowg = m0 + wr * 32 + m * 16 + 4 * l4 + i;
        out[(size_t)rowg * DMODEL + colg] = acc[m][n][i] + bn;
      }
    }
  }
}

// ------------- flash attention (causal), split-KV across 4 waves -------------
// Block = one 32-row q-tile of one bh; wave w handles kv tiles {w, w+4, ...}.
// Private (m,l,O) per wave; one barrier; LDS merge with exp rescale.
// Opart ALIASES Pl (P is dead after a wave's KV loop) -> 19.5 KB LDS.
// No forced wave cap: (256,2) keeps VGPR <= 256, avoiding R4's scratch spills.
// tt = 63-(id>>5): longest blocks dispatch first (tail removal).
__global__ __launch_bounds__(256, 2) void attn_kernel(const u16* __restrict__ Qh,
                                                      const u16* __restrict__ Kh,
                                                      const u16* __restrict__ Vt,
                                                      u16* __restrict__ Ob) {
  __shared__ __align__(16) u16 Pl[4][32][72];  // doubles as Opart after loop
  __shared__ float Ml[4][32];
  __shared__ float Ll[4][32];
  const int tixd = threadIdx.x;
  const int wave = tixd >> 6, lane = tixd & 63;
  const int l15 = lane & 15, l4 = lane >> 4;
  const int id = blockIdx.x;
  const int bh = (id & 7) * 4 + ((id >> 3) & 3);  // XCD-local heads
  const int tt = 63 - (id >> 5);                  // longest-first
  const int q0 = tt * 32;
  const int ntile = (tt >> 1) + 1;
  const u16* Qb = Qh + (size_t)bh * S_LEN * HSZ;
  const u16* Kb = Kh + (size_t)bh * S_LEN * HSZ;
  const u16* Vb = Vt + (size_t)bh * HSZ * S_LEN;
  const int shbase = l4 * 20;  // lane with l15' = 4*l4+i, same l4
  u16 (*P)[72] = Pl[wave];

  bf16x8 qf[2][2];
#pragma unroll
  for (int m = 0; m < 2; ++m)
#pragma unroll
    for (int kc = 0; kc < 2; ++kc)
      qf[m][kc] = *(const bf16x8*)(Qb + (size_t)(q0 + m * 16 + l15) * HSZ + kc * 32 + l4 * 8);

  f32x4 oacc[2][4] = {};
  float mrun[2] = {-1e30f, -1e30f};
  float lrun[2] = {0.f, 0.f};

  auto loadK = [&](int kv0, bf16x8 (&kf)[4][2]) {
#pragma unroll
    for (int n = 0; n < 4; ++n)
#pragma unroll
      for (int kc = 0; kc < 2; ++kc)
        kf[n][kc] = *(const bf16x8*)(Kb + (size_t)(kv0 + n * 16 + l15) * HSZ + kc * 32 + l4 * 8);
  };

  auto process = [&](int kv0, bf16x8 (&kf)[4][2]) {
    f32x4 sacc[2][4] = {};
#pragma unroll
    for (int m = 0; m < 2; ++m)
#pragma unroll
      for (int n = 0; n < 4; ++n) {
        sacc[m][n] = mfma16(kf[n][0], qf[m][0], sacc[m][n]);
        sacc[m][n] = mfma16(kf[n][1], qf[m][1], sacc[m][n]);
      }
    // V fragments issued here: latency hides under mask+softmax chain
    bf16x8 vf[2][4];
#pragma unroll
    for (int kb = 0; kb < 2; ++kb)
#pragma unroll
      for (int n = 0; n < 4; ++n)
        vf[kb][n] = *(const bf16x8*)(Vb + (size_t)(n * 16 + l15) * S_LEN + kv0 + kb * 32 + l4 * 8);
    if (kv0 + 63 > q0) {
#pragma unroll
      for (int m = 0; m < 2; ++m)
#pragma unroll
        for (int n = 0; n < 4; ++n)
#pragma unroll
          for (int i = 0; i < 4; ++i)
            if (kv0 + n * 16 + 4 * l4 + i > q0 + m * 16 + l15) sacc[m][n][i] = -1e30f;
    }
#pragma unroll
    for (int m = 0; m < 2; ++m) {
      float tm = sacc[m][0][0];
#pragma unroll
      for (int n = 0; n < 4; ++n)
#pragma unroll
        for (int i = 0; i < 4; ++i) tm = fmaxf(tm, sacc[m][n][i]);
      tm = fmaxf(tm, __shfl_xor(tm, 16));
      tm = fmaxf(tm, __shfl_xor(tm, 32));
      float mnew = fmaxf(mrun[m], tm);
      float corr = __expf(mrun[m] - mnew);
      mrun[m] = mnew;
      float rs = 0.f;
#pragma unroll
      for (int n = 0; n < 4; ++n)
#pragma unroll
        for (int i = 0; i < 4; ++i) {
          float p = __expf(sacc[m][n][i] - mnew);
          sacc[m][n][i] = p;
          rs += p;
        }
      rs += __shfl_xor(rs, 16);
      rs += __shfl_xor(rs, 32);
      lrun[m] = lrun[m] * corr + rs;
      float c0 = __shfl(corr, shbase + 0);
      float c1 = __shfl(corr, shbase + 1);
      float c2 = __shfl(corr, shbase + 2);
      float c3 = __shfl(corr, shbase + 3);
#pragma unroll
      for (int n = 0; n < 4; ++n) {
        oacc[m][n][0] *= c0; oacc[m][n][1] *= c1;
        oacc[m][n][2] *= c2; oacc[m][n][3] *= c3;
      }
#pragma unroll
      for (int n = 0; n < 4; ++n) {
        ushort4 pk;
        pk.x = f2bf(sacc[m][n][0]); pk.y = f2bf(sacc[m][n][1]);
        pk.z = f2bf(sacc[m][n][2]); pk.w = f2bf(sacc[m][n][3]);
        *(ushort4*)&P[m * 16 + l15][n * 16 + 4 * l4] = pk;
      }
    }
#pragma unroll
    for (int kb = 0; kb < 2; ++kb) {
      bf16x8 pf0 = *(const bf16x8*)&P[l15][kb * 32 + l4 * 8];
      bf16x8 pf1 = *(const bf16x8*)&P[16 + l15][kb * 32 + l4 * 8];
#pragma unroll
      for (int n = 0; n < 4; ++n) {
        oacc[0][n] = mfma16(pf0, vf[kb][n], oacc[0][n]);
        oacc[1][n] = mfma16(pf1, vf[kb][n], oacc[1][n]);
      }
    }
  };

  const int nt = (ntile > wave) ? ((ntile - wave + 3) >> 2) : 0;
  bf16x8 kA[4][2];
  for (int j = 0; j < nt; ++j) {
    const int kv0 = (wave + 4 * j) * 64;
    loadK(kv0, kA);
    process(kv0, kA);
  }

  // publish partials; Opart aliases Pl (P dead now for this wave)
  if (l4 == 0) {
#pragma unroll
    for (int m = 0; m < 2; ++m) {
      Ml[wave][m * 16 + l15] = mrun[m];
      Ll[wave][m * 16 + l15] = lrun[m];
    }
  }
#pragma unroll
  for (int m = 0; m < 2; ++m)
#pragma unroll
    for (int n = 0; n < 4; ++n)
#pragma unroll
      for (int i = 0; i < 4; ++i)
        Pl[wave][m * 16 + 4 * l4 + i][n * 16 + l15] = f2bf(oacc[m][n][i]);
  __syncthreads();

  // merge: thread t -> row r = t>>3, col chunk c0 = (t&7)*8
  {
    const int r = tixd >> 3;
    const int c0 = (tixd & 7) * 8;
    float m0v = Ml[0][r], m1v = Ml[1][r], m2v = Ml[2][r], m3v = Ml[3][r];
    float M = fmaxf(fmaxf(m0v, m1v), fmaxf(m2v, m3v));
    float e0 = __expf(m0v - M), e1 = __expf(m1v - M);
    float e2 = __expf(m2v - M), e3 = __expf(m3v - M);
    float L = Ll[0][r] * e0 + Ll[1][r] * e1 + Ll[2][r] * e2 + Ll[3][r] * e3;
    float invL = 1.0f / L;
    bf16x8 o0 = *(const bf16x8*)&Pl[0][r][c0];
    bf16x8 o1 = *(const bf16x8*)&Pl[1][r][c0];
    bf16x8 o2 = *(const bf16x8*)&Pl[2][r][c0];
    bf16x8 o3 = *(const bf16x8*)&Pl[3][r][c0];
    const int b = bh >> 4, h = bh & 15;
    const int srow = q0 + r;
    u16* dst = Ob + ((size_t)b * S_LEN + srow) * DMODEL + h * HSZ + c0;
    ushort4 w0, w1;
    u16* wp[2] = {(u16*)&w0, (u16*)&w1};
#pragma unroll
    for (int j = 0; j < 8; ++j) {
      float acc = bf2f(((u16*)&o0)[j]) * e0;
      acc += bf2f(((u16*)&o1)[j]) * e1;
      acc += bf2f(((u16*)&o2)[j]) * e2;
      acc += bf2f(((u16*)&o3)[j]) * e3;
      wp[j >> 2][j & 3] = f2bf(acc * invL);
    }
    *(ushort4*)(dst + 0) = w0;
    *(ushort4*)(dst + 4) = w1;
  }
}

extern "C" void kernel_launch(void* const* d_in, const int* in_sizes, int n_in,
                              void* d_out, int out_size, void* d_ws, size_t ws_size,
                              hipStream_t stream) {
  const float* q  = (const float*)d_in[0];
  const float* Wq = (const float*)d_in[1];
  const float* bq = (const float*)d_in[2];
  const float* Wk = (const float*)d_in[3];
  const float* bk = (const float*)d_in[4];
  const float* Wv = (const float*)d_in[5];
  const float* bv = (const float*)d_in[6];
  const float* Wo = (const float*)d_in[7];
  const float* bo = (const float*)d_in[8];

  char* ws = (char*)d_ws;
  const size_t MB = 1024 * 1024;
  u16* Xb  = (u16*)(ws + 0);        // 8 MB  [4096][1024] bf16
  u16* WqT = (u16*)(ws + 8 * MB);   // 2 MB  [N][K] bf16
  u16* WkT = (u16*)(ws + 10 * MB);
  u16* WvT = (u16*)(ws + 12 * MB);
  u16* WoT = (u16*)(ws + 14 * MB);
  u16* Qh  = (u16*)(ws + 16 * MB);  // 8 MB  [bh][S][64]
  u16* Kh  = (u16*)(ws + 24 * MB);
  u16* Vh  = (u16*)(ws + 32 * MB);
  u16* Vt  = (u16*)(ws + 40 * MB);  // 8 MB  [bh][64][S]
  u16* Ob  = (u16*)(ws + 48 * MB);  // 8 MB  [B,S,D]

  convert_f2b_kernel<<<4096, 256, 0, stream>>>(q, Xb);
  transpose_w_kernel<<<dim3(16, 16, 4), 256, 0, stream>>>(Wq, Wk, Wv, Wo,
                                                          WqT, WkT, WvT, WoT);
  gemm_qkv_kernel<<<dim3(8, 32, 3), 256, 0, stream>>>(Xb, WqT, WkT, WvT,
                                                      bq, bk, bv, Qh, Kh, Vh);
  transpose_v_kernel<<<dim3(32, 32), 256, 0, stream>>>(Vh, Vt);
  attn_kernel<<<2048, 256, 0, stream>>>(Qh, Kh, Vt, Ob);
  gemm_out_kernel<<<dim3(8, 64), 256, 0, stream>>>(Ob, WoT, bo, (float*)d_out);
}